// Round 15
// baseline (1494.677 us; speedup 1.0000x reference)
//
#include <hip/hip_runtime.h>

#define T_ 512
#define K_ 128
#define B_ 256

// Persistent intermediates in module-static device memory (no hipMalloc,
// no dependence on ws_size). v-scores are exact fp32 -> bp recompute is
// bit-identical to an in-loop argmax (same float operands, same tournament).
__device__ float         g_v[B_][T_][K_];   // viterbi max-scores (64 MB)
__device__ unsigned char g_bp[B_][T_][K_];  // backpointers (16 MB)

// History: 697 (R5 fused 8-wave) -> 548 (R8 role-split 4-wave) -> 494.6 (R10
// skew+tournament) -> R11 C=2 658 (reverted) -> R12 decorrelation null.
// Diagnosis: per-step cost is the barrier-coupled LDS round-trip (domain 8->4
// waves saved 700 cyc/step; throughput edits null/negative). This round:
// domain -> 1 wave. A single wave is lockstep: single-buffer LDS state,
// program-order write->read, ZERO barriers in the serial loop. Viterbi keeps
// only the VALUE recurrence in the serial loop (max is exactly associative);
// backpointers are recomputed massively parallel in crf_bp from streamed v.

// ---------------- kernel 1: serial recurrences, one wave per role ----------
__global__ __launch_bounds__(64, 1) void crf_serial(
    const float* __restrict__ emissions,
    const int* __restrict__ lengths,
    const float* __restrict__ transitions,
    float* __restrict__ ws_logZ)
{
    const int bid = blockIdx.x;
    const int l   = threadIdx.x;            // lane 0..63

    if (bid < B_) {
        // ---------- FORWARD (logsumexp) ----------
        __shared__ __align__(16) float ea[K_];   // exp(alpha - S), single buffer
        const int b   = bid;
        const int len = lengths[b];
        const float* emB = emissions + (size_t)b * T_ * K_;

        // lane l owns columns {l, l+64}: exp(T[i][col]) for all i, in registers
        float tA[128], tB[128];
        #pragma unroll
        for (int i = 0; i < 128; ++i) {
            tA[i] = __expf(transitions[i * K_ + l]);
            tB[i] = __expf(transitions[i * K_ + l + 64]);
        }

        float e0 = emB[l], e1 = emB[l + 64];
        ea[l]      = __expf(e0);            // offset S0 = 0
        ea[l + 64] = __expf(e1);
        float wm = fmaxf(e0, e1);
        #pragma unroll
        for (int m = 1; m < 64; m <<= 1) wm = fmaxf(wm, __shfl_xor(wm, m));
        float Wm = wm;                      // next-window scale (all lanes hold it)
        float Sr = 0.f;                     // scale of current ea

        float eN0 = emB[K_ + l], eN1 = emB[K_ + l + 64];   // prefetch t = 1

        for (int t = 1; t < len; ++t) {
            float ec0 = eN0, ec1 = eN1;
            int tn = (t + 1 < T_) ? (t + 1) : t;
            eN0 = emB[tn * K_ + l]; eN1 = emB[tn * K_ + l + 64];

            float Sw = (((t - 1) & 3) == 0) ? Wm : Sr;     // defer-max cadence 4

            float a0=0.f,a1=0.f,a2=0.f,a3=0.f, c0=0.f,c1=0.f,c2=0.f,c3=0.f;
            #pragma unroll
            for (int m = 0; m < 32; ++m) {
                float4 q = *(const float4*)&ea[4 * m];     // broadcast read
                a0 = fmaf(q.x, tA[4*m+0], a0);
                a1 = fmaf(q.y, tA[4*m+1], a1);
                a2 = fmaf(q.z, tA[4*m+2], a2);
                a3 = fmaf(q.w, tA[4*m+3], a3);
                c0 = fmaf(q.x, tB[4*m+0], c0);
                c1 = fmaf(q.y, tB[4*m+1], c1);
                c2 = fmaf(q.z, tB[4*m+2], c2);
                c3 = fmaf(q.w, tB[4*m+3], c3);
            }
            float d0 = (a0 + a1) + (a2 + a3);
            float d1 = (c0 + c1) + (c2 + c3);
            float an0 = __logf(d0) + Sr + ec0;
            float an1 = __logf(d1) + Sr + ec1;
            // writes execute after all reads (wave-lockstep, program order)
            ea[l]      = __expf(an0 - Sw);
            ea[l + 64] = __expf(an1 - Sw);
            Sr = Sw;
            if (((t - 1) & 3) == 3) {                      // publish window max
                float w = fmaxf(an0, an1);
                #pragma unroll
                for (int m = 1; m < 64; m <<= 1) w = fmaxf(w, __shfl_xor(w, m));
                Wm = w;
            }
        }
        float s = ea[l] + ea[l + 64];
        #pragma unroll
        for (int m = 1; m < 64; m <<= 1) s += __shfl_xor(s, m);
        if (l == 0) ws_logZ[b] = Sr + __logf(s);

    } else {
        // ---------- VITERBI, value recurrence only ----------
        __shared__ __align__(16) float va[K_];  // single buffer
        const int b   = bid - B_;
        const int len = lengths[b];
        const float* emB = emissions + (size_t)b * T_ * K_;

        float tA[128], tB[128];
        #pragma unroll
        for (int i = 0; i < 128; ++i) {
            tA[i] = transitions[i * K_ + l];
            tB[i] = transitions[i * K_ + l + 64];
        }

        float v0 = emB[l], v1 = emB[l + 64];
        va[l] = v0; va[l + 64] = v1;
        g_v[b][0][l] = v0; g_v[b][0][l + 64] = v1;

        float eN0 = emB[K_ + l], eN1 = emB[K_ + l + 64];

        for (int t = 1; t < len; ++t) {
            float ec0 = eN0, ec1 = eN1;
            int tn = (t + 1 < T_) ? (t + 1) : t;
            eN0 = emB[tn * K_ + l]; eN1 = emB[tn * K_ + l + 64];

            // max_i(va[i] + T[i][col]) — fp max is exactly associative, so any
            // grouping gives the bit-identical value the argmax path selects.
            float r0 = -3.4028235e38f, r1 = r0, r2 = r0, r3 = r0;
            #pragma unroll
            for (int m = 0; m < 32; ++m) {
                float4 q = *(const float4*)&va[4 * m];
                r0 = fmaxf(r0, fmaxf(q.x + tA[4*m+0], q.y + tA[4*m+1]));
                r1 = fmaxf(r1, fmaxf(q.z + tA[4*m+2], q.w + tA[4*m+3]));
                r2 = fmaxf(r2, fmaxf(q.x + tB[4*m+0], q.y + tB[4*m+1]));
                r3 = fmaxf(r3, fmaxf(q.z + tB[4*m+2], q.w + tB[4*m+3]));
            }
            float vn0 = fmaxf(r0, r1) + ec0;
            float vn1 = fmaxf(r2, r3) + ec1;
            va[l] = vn0; va[l + 64] = vn1;
            g_v[b][t][l] = vn0; g_v[b][t][l + 64] = vn1;   // fire-and-forget
        }
    }
}

// -------- kernel 2: backpointer recompute (parallel over t, no chain) ------
__global__ __launch_bounds__(256, 2) void crf_bp(
    const int* __restrict__ lengths,
    const float* __restrict__ transitions)
{
    const int b     = blockIdx.x >> 2;
    const int chunk = blockIdx.x & 3;
    const int len   = lengths[b];
    const int tid   = threadIdx.x;
    const int j = tid >> 1;
    const int c = tid & 1;

    int t0 = 1 + chunk * 128;
    int t1 = t0 + 128; if (t1 > len) t1 = len;
    if (t0 >= t1) return;

    float tbl[64];
    #pragma unroll
    for (int k = 0; k < 64; ++k)
        tbl[k] = transitions[(c * 64 + k) * K_ + j];

    for (int t = t0; t < t1; ++t) {
        const float* vp = &g_v[b][t - 1][c * 64];
        // exact R10 first-max tournament (identical float operands as an
        // in-loop argmax -> identical backpointers)
        float v0[16]; int gg[16];
        #pragma unroll
        for (int k = 0; k < 16; ++k) {
            float4 v4 = *(const float4*)(vp + 4 * k);
            float s0 = v4.x + tbl[4*k+0];
            float s1 = v4.y + tbl[4*k+1];
            float s2 = v4.z + tbl[4*k+2];
            float s3 = v4.w + tbl[4*k+3];
            float mA; int aA;
            if (s1 > s0) { mA = s1; aA = 4*k+1; } else { mA = s0; aA = 4*k+0; }
            float mC; int aC;
            if (s3 > s2) { mC = s3; aC = 4*k+3; } else { mC = s2; aC = 4*k+2; }
            if (mC > mA) { v0[k] = mC; gg[k] = aC; } else { v0[k] = mA; gg[k] = aA; }
        }
        #pragma unroll
        for (int st = 1; st < 16; st <<= 1) {
            #pragma unroll
            for (int k = 0; k < 16; k += 2 * st) {
                if (v0[k+st] > v0[k]) { v0[k] = v0[k+st]; gg[k] = gg[k+st]; }
            }
        }
        float mB = v0[0];
        int  arg = gg[0] + c * 64;
        float om = __shfl_xor(mB, 1);
        int   oa = __shfl_xor(arg, 1);
        float mLow  = c ? om : mB;   int aLow  = c ? oa : arg;   // low-i wins ties
        float mHigh = c ? mB : om;   int aHigh = c ? arg : oa;
        int aF = (mHigh > mLow) ? aHigh : aLow;
        if (c == 0) g_bp[b][t][j] = (unsigned char)aF;
    }
}

// -------- kernel 3: backtrace + decode + accuracy + sequence score ---------
__global__ __launch_bounds__(256, 2) void crf_back(
    const float* __restrict__ emissions,
    const int* __restrict__ tag_ids,
    const int* __restrict__ lengths,
    const float* __restrict__ transitions,
    float* __restrict__ out,
    float* __restrict__ ws_ll,
    int* __restrict__ ws_cnt,
    const float* __restrict__ ws_logZ)
{
    __shared__ __align__(16) unsigned char bpL[T_ * K_];   // 64 KB
    __shared__ unsigned char decL[T_];
    __shared__ float redS[4];
    __shared__ int  redI[4];
    __shared__ int  ltag;

    const int b   = blockIdx.x;
    const int tid = threadIdx.x;
    const int len = lengths[b];
    const float* emB = emissions + (size_t)b * T_ * K_;
    const int*  tagB = tag_ids + b * T_;

    // bulk-load backpointers into LDS
    {
        const uint4* src = (const uint4*)&g_bp[b][0][0];
        uint4* dst = (uint4*)&bpL[0];
        #pragma unroll
        for (int it = 0; it < 16; ++it)
            dst[it * 256 + tid] = src[it * 256 + tid];
    }

    // sequence score (unary + binary), 2 t per thread
    {
        float s = 0.f;
        #pragma unroll
        for (int h = 0; h < 2; ++h) {
            int t = tid + h * 256;
            if (t < len) {
                int tg = tagB[t];
                float v = emB[t * K_ + tg];
                if (t >= 1) v += transitions[tagB[t - 1] * K_ + tg];
                s += v;
            }
        }
        #pragma unroll
        for (int m = 1; m < 64; m <<= 1) s += __shfl_xor(s, m);
        if ((tid & 63) == 0) redS[tid >> 6] = s;
    }

    // last tag: first-max over final viterbi scores
    if (tid < 64) {
        const float* vf = &g_v[b][len - 1][0];
        int l = tid;
        float m = vf[l]; int a = l;
        float v2 = vf[l + 64];
        if (v2 > m) { m = v2; a = l + 64; }
        #pragma unroll
        for (int sft = 1; sft < 64; sft <<= 1) {
            float om = __shfl_xor(m, sft);
            int   oa = __shfl_xor(a, sft);
            if (om > m || (om == m && oa < a)) { m = om; a = oa; }
        }
        if (l == 0) ltag = a;
    }
    __syncthreads();

    // backtrace (serial chain through LDS)
    if (tid == 0) {
        int tg = ltag;
        for (int t = T_ - 1; t >= 1; --t) {
            decL[t] = (unsigned char)tg;
            if (t < len) tg = bpL[t * K_ + tg];   // identity bp for t >= len
        }
        decL[0] = (unsigned char)tg;
    }
    __syncthreads();

    // decoded write + accuracy count
    {
        int good = 0;
        #pragma unroll
        for (int h = 0; h < 2; ++h) {
            int t = tid + h * 256;
            int dv = decL[t];
            out[1 + b * T_ + t] = (float)dv;
            good += (t < len && tagB[t] == dv) ? 1 : 0;
        }
        #pragma unroll
        for (int m = 1; m < 64; m <<= 1) good += __shfl_xor(good, m);
        if ((tid & 63) == 0) redI[tid >> 6] = good;
    }
    __syncthreads();

    if (tid == 0) {
        ws_cnt[b] = redI[0] + redI[1] + redI[2] + redI[3];
        ws_ll[b]  = (redS[0] + redS[1] + redS[2] + redS[3]) - ws_logZ[b];
    }
}

// Final reduction: loss = -mean(ll), accuracy = sum(correct)/sum(len)
__global__ void crf_final(const float* __restrict__ ws_ll,
                          const int* __restrict__ ws_cnt,
                          const int* __restrict__ lengths,
                          float* __restrict__ out)
{
    __shared__ float sll[4];
    __shared__ int scnt[4], slen[4];
    int tid = threadIdx.x;                            // blockDim == B_ == 256
    float ll = ws_ll[tid];
    int   cn = ws_cnt[tid];
    int   L  = lengths[tid];
    #pragma unroll
    for (int m = 1; m < 64; m <<= 1) {
        ll += __shfl_xor(ll, m);
        cn += __shfl_xor(cn, m);
        L  += __shfl_xor(L, m);
    }
    if ((tid & 63) == 0) { sll[tid >> 6] = ll; scnt[tid >> 6] = cn; slen[tid >> 6] = L; }
    __syncthreads();
    if (tid == 0) {
        float llS = sll[0] + sll[1] + sll[2] + sll[3];
        int   cS  = scnt[0] + scnt[1] + scnt[2] + scnt[3];
        int   LS  = slen[0] + slen[1] + slen[2] + slen[3];
        out[0] = -llS / (float)B_;
        out[1 + B_ * T_] = (float)cS / (float)LS;
    }
}

extern "C" void kernel_launch(void* const* d_in, const int* in_sizes, int n_in,
                              void* d_out, int out_size, void* d_ws, size_t ws_size,
                              hipStream_t stream) {
    const float* emissions   = (const float*)d_in[0];
    const int*   tag_ids     = (const int*)d_in[1];
    const int*   lengths     = (const int*)d_in[2];
    const float* transitions = (const float*)d_in[3];
    float* out = (float*)d_out;

    float* ws_ll   = (float*)d_ws;
    int*   ws_cnt  = (int*)((char*)d_ws + B_ * sizeof(float));
    float* ws_logZ = (float*)((char*)d_ws + 2 * B_ * sizeof(float));

    crf_serial<<<2 * B_, 64, 0, stream>>>(emissions, lengths, transitions, ws_logZ);
    crf_bp<<<4 * B_, 256, 0, stream>>>(lengths, transitions);
    crf_back<<<B_, 256, 0, stream>>>(emissions, tag_ids, lengths, transitions,
                                     out, ws_ll, ws_cnt, ws_logZ);
    crf_final<<<1, B_, 0, stream>>>(ws_ll, ws_cnt, lengths, out);
}